// Round 11
// baseline (47.120 us; speedup 1.0000x reference)
//
#include <hip/hip_runtime.h>
#include <math.h>

#define IMG_H 768
#define IMG_W 768
#define BATCH 16
#define TH 4                         // output rows per strip
#define TPB 256                      // 4 waves; wave w computes strip row w, stages image w
#define NBLK 256                     // 1 block/CU; block b: batch b>>4, y-strips (b&15)*12 ..+11
#define SPB 12                       // strips per block (192 y-strips / 16)
#define NPIX ((size_t)BATCH * IMG_H * IMG_W)  // 9437184

typedef const __attribute__((address_space(1))) float* gp1_t;
typedef __attribute__((address_space(3))) float* lp3_t;

#define SBAR()   __builtin_amdgcn_s_barrier()
#define SCHEDB() __builtin_amdgcn_sched_barrier(0)
#define WAIT_VM18() asm volatile("s_waitcnt vmcnt(18)" ::: "memory")
#define WAIT_VM0()  asm volatile("s_waitcnt vmcnt(0)"  ::: "memory")
#define WAIT_LGKM0() asm volatile("s_waitcnt lgkmcnt(0)" ::: "memory")

// Wave stages its image's 6 rows x 3 segs = 18 x 1KB DMA chunks (no VGPR payload).
__device__ __forceinline__ void stage_img(const float* __restrict__ ip,
                                          float (*buf)[IMG_W], int y0, int lane) {
    #pragma unroll
    for (int i = 0; i < 18; ++i) {
        const int row = i / 3, seg = i % 3;
        int gr = y0 - 1 + row;
        int rc = gr < 0 ? 0 : (gr > IMG_H - 1 ? IMG_H - 1 : gr);   // clamp; OOB zeroed later
        const float* src = ip + (size_t)rc * IMG_W + seg * 256 + lane * 4;
        __builtin_amdgcn_global_load_lds((gp1_t)src, (lp3_t)&buf[row][seg * 256], 16, 0, 0);
    }
}

// Wave wv computes output row y0+wv (full 768 px, 12 px/lane) from a staged strip.
__device__ __forceinline__ void compute_strip(const float (*buf)[TH + 2][IMG_W],
                                              int wv, int lane,
                                              float& sX2, float& sY2, float& sL1) {
    const int r0 = wv, r1 = wv + 1, r2 = wv + 2;
    const int xb = lane * 12;
    float jnt[12];
    #pragma unroll
    for (int im = 0; im < 4; ++im) {
        float4 t0 = *(const float4*)&buf[im][r0][xb];
        float4 t1 = *(const float4*)&buf[im][r0][xb + 4];
        float4 t2 = *(const float4*)&buf[im][r0][xb + 8];
        float4 m0 = *(const float4*)&buf[im][r1][xb];
        float4 m1 = *(const float4*)&buf[im][r1][xb + 4];
        float4 m2 = *(const float4*)&buf[im][r1][xb + 8];
        float4 b0 = *(const float4*)&buf[im][r2][xb];
        float4 b1 = *(const float4*)&buf[im][r2][xb + 4];
        float4 b2 = *(const float4*)&buf[im][r2][xb + 8];

        float T[14], M[14], B[14];
        T[1] = t0.x; T[2] = t0.y; T[3] = t0.z; T[4] = t0.w;
        T[5] = t1.x; T[6] = t1.y; T[7] = t1.z; T[8] = t1.w;
        T[9] = t2.x; T[10] = t2.y; T[11] = t2.z; T[12] = t2.w;
        M[1] = m0.x; M[2] = m0.y; M[3] = m0.z; M[4] = m0.w;
        M[5] = m1.x; M[6] = m1.y; M[7] = m1.z; M[8] = m1.w;
        M[9] = m2.x; M[10] = m2.y; M[11] = m2.z; M[12] = m2.w;
        B[1] = b0.x; B[2] = b0.y; B[3] = b0.z; B[4] = b0.w;
        B[5] = b1.x; B[6] = b1.y; B[7] = b1.z; B[8] = b1.w;
        B[9] = b2.x; B[10] = b2.y; B[11] = b2.z; B[12] = b2.w;

        float tl = __shfl_up(t2.w, 1),  tr = __shfl_down(t0.x, 1);
        float ml = __shfl_up(m2.w, 1),  mr = __shfl_down(m0.x, 1);
        float bl = __shfl_up(b2.w, 1),  br = __shfl_down(b0.x, 1);
        T[0] = (lane == 0) ? 0.f : tl;  T[13] = (lane == 63) ? 0.f : tr;
        M[0] = (lane == 0) ? 0.f : ml;  M[13] = (lane == 63) ? 0.f : mr;
        B[0] = (lane == 0) ? 0.f : bl;  B[13] = (lane == 63) ? 0.f : br;

        float s[14], d[14];
        #pragma unroll
        for (int j = 0; j < 14; ++j) { s[j] = T[j] + B[j]; d[j] = T[j] - B[j]; }

        float g[12];
        #pragma unroll
        for (int j = 0; j < 12; ++j) {
            float gx = (s[j + 2] - s[j]) + 2.f * (M[j + 2] - M[j]);
            float gy = d[j] + 2.f * d[j + 1] + d[j + 2];
            g[j] = fabsf(gx) + fabsf(gy);
        }
        if (im == 0) {
            #pragma unroll
            for (int j = 0; j < 12; ++j) jnt[j] = g[j];
        } else if (im == 1) {
            #pragma unroll
            for (int j = 0; j < 12; ++j) jnt[j] = fmaxf(jnt[j], g[j]);
        } else if (im == 2) {
            #pragma unroll
            for (int j = 0; j < 12; ++j) { sX2 += g[j] * g[j]; sL1 += fabsf(g[j] - jnt[j]); }
        } else {
            #pragma unroll
            for (int j = 0; j < 12; ++j) sY2 += g[j] * g[j];
        }
    }
}

__global__ __launch_bounds__(TPB) void sobel_loss_fused(
    const float* __restrict__ vis, const float* __restrict__ ir,
    const float* __restrict__ X, const float* __restrict__ Y,
    float* __restrict__ part, unsigned* __restrict__ counter,
    float* __restrict__ out)
{
    __shared__ __align__(16) float bufA[4][TH + 2][IMG_W];   // 73728 B
    __shared__ __align__(16) float bufB[4][TH + 2][IMG_W];   // 73728 B
    __shared__ float red[3][4];
    __shared__ int lastLds;

    const int tid  = threadIdx.x;
    const int lane = tid & 63;
    const int wv   = tid >> 6;
    const int b    = blockIdx.x;
    const int ib   = b >> 4;                  // batch image
    const int ys0  = (b & 15) * SPB;          // first y-strip (consecutive walk)
    const size_t base = (size_t)ib * (IMG_H * IMG_W);
    const float* img0[4] = { vis + base, ir + base, X + base, Y + base };
    const float* ip = img0[wv];               // wave wv stages image wv

    float sX2 = 0.f, sY2 = 0.f, sL1 = 0.f;

    stage_img(ip, bufA[wv], ys0 * TH, lane);  // prologue: strip 0 in flight (18/wave)

    #pragma unroll 1
    for (int t = 0; t < SPB / 2; ++t) {
        const int y0A = (ys0 + 2 * t) * TH;
        const int y0B = y0A + TH;

        // ---- phase A: prefetch strip B, compute strip A ----
        stage_img(ip, bufB[wv], y0B, lane);   // 18 more in flight
        WAIT_VM18();                          // strip A's 18 landed; B's still flying
        SBAR(); SCHEDB();
        if (y0A == 0) {                       // zero top halo (block-uniform, rare)
            for (int i = tid; i < 4 * IMG_W; i += TPB) bufA[i / IMG_W][0][i % IMG_W] = 0.f;
            WAIT_LGKM0(); SBAR();
        }
        compute_strip((const float (*)[TH + 2][IMG_W])bufA, wv, lane, sX2, sY2, sL1);
        SCHEDB(); SBAR();                     // all reads of bufA done before its re-stage

        // ---- phase B: prefetch next strip A, compute strip B ----
        if (t < SPB / 2 - 1) {
            stage_img(ip, bufA[wv], y0B + TH, lane);
            WAIT_VM18();
        } else {
            WAIT_VM0();
        }
        SBAR(); SCHEDB();
        if (y0B + TH == IMG_H) {              // zero bottom halo (block-uniform, rare)
            for (int i = tid; i < 4 * IMG_W; i += TPB) bufB[i / IMG_W][TH + 1][i % IMG_W] = 0.f;
            WAIT_LGKM0(); SBAR();
        }
        compute_strip((const float (*)[TH + 2][IMG_W])bufB, wv, lane, sX2, sY2, sL1);
        SCHEDB(); SBAR();
    }

    // ---- block partial reduce (no DMA outstanding now; normal syncs are safe) ----
    #pragma unroll
    for (int off = 32; off > 0; off >>= 1) {
        sX2 += __shfl_down(sX2, off);
        sY2 += __shfl_down(sY2, off);
        sL1 += __shfl_down(sL1, off);
    }
    if (lane == 0) { red[0][wv] = sX2; red[1][wv] = sY2; red[2][wv] = sL1; }
    __syncthreads();
    if (tid == 0) {
        part[0 * NBLK + b] = red[0][0] + red[0][1] + red[0][2] + red[0][3];
        part[1 * NBLK + b] = red[1][0] + red[1][1] + red[1][2] + red[1][3];
        part[2 * NBLK + b] = red[2][0] + red[2][1] + red[2][2] + red[2][3];
        __threadfence();                                  // publish partials (device scope)
        unsigned tk = atomicAdd(counter, 1u);
        lastLds = (tk == NBLK - 1);
    }
    __syncthreads();

    // ---- last block finishes: 256 partials, one per thread ----
    if (lastLds) {
        __threadfence();                                  // acquire other blocks' stores
        float a = part[0 * NBLK + tid];
        float c2 = part[1 * NBLK + tid];
        float c3 = part[2 * NBLK + tid];
        #pragma unroll
        for (int off = 32; off > 0; off >>= 1) {
            a  += __shfl_down(a,  off);
            c2 += __shfl_down(c2, off);
            c3 += __shfl_down(c3, off);
        }
        if (lane == 0) { red[0][wv] = a; red[1][wv] = c2; red[2][wv] = c3; }
        __syncthreads();
        if (tid == 0) {
            float sa = red[0][0] + red[0][1] + red[0][2] + red[0][3];
            float sb = red[1][0] + red[1][1] + red[1][2] + red[1][3];
            float sc = red[2][0] + red[2][1] + red[2][2] + red[2][3];
            out[0] = sb / sa;                      // loss_in = sumY2 / sumX2
            out[1] = sc * (1.f / (float)NPIX);     // loss_grad = sumL1 / N
        }
    }
}

extern "C" void kernel_launch(void* const* d_in, const int* in_sizes, int n_in,
                              void* d_out, int out_size, void* d_ws, size_t ws_size,
                              hipStream_t stream) {
    const float* vis = (const float*)d_in[0];
    const float* ir  = (const float*)d_in[1];
    const float* X   = (const float*)d_in[2];
    const float* Y   = (const float*)d_in[3];
    float* out = (float*)d_out;

    unsigned* counter = (unsigned*)d_ws;
    float* part = (float*)((char*)d_ws + 256);   // 3 * 256 floats

    hipMemsetAsync(counter, 0, sizeof(unsigned), stream);  // ws not re-poisoned between replays
    sobel_loss_fused<<<NBLK, TPB, 0, stream>>>(vis, ir, X, Y, part, counter, out);
}